// Round 4
// baseline (6273.895 us; speedup 1.0000x reference)
//
#include <hip/hip_runtime.h>
#include <hip/hip_bf16.h>
#include <math.h>

#define CC_ 128
#define HH_ 128
#define WW_ 128
#define BB_ 8
#define NPLANE (HH_*WW_)          // 16384
#define NTOT (BB_*CC_*NPLANE)     // 16777216

typedef unsigned short u16;
typedef unsigned int u32;

__device__ __forceinline__ float b2f(u16 u) {
  u32 x = ((u32)u) << 16;
  return __builtin_bit_cast(float, x);
}
__device__ __forceinline__ u16 f2b(float f) {
  u32 x = __builtin_bit_cast(u32, f);
  u32 r = (x + 0x7FFFu + ((x >> 16) & 1u)) >> 16;   // RNE
  return (u16)r;
}

// ---------------------------------------------------------------------------
// conv3x3, pad=1: tile 32(y) x 16(x) spatial, 32 oc per block.
// TIN/TOUT: 0 = f32, 1 = bf16. ACT: 0 = none, 1 = sigmoid.
// ---------------------------------------------------------------------------
template<int ACT, int TIN_BF, int TOUT_BF>
__global__ __launch_bounds__(256) void conv3x3_kernel(
    const void* __restrict__ in_, const float* __restrict__ w,
    const float* __restrict__ bias, void* __restrict__ out_)
{
  const float* inf = (const float*)in_;
  const u16*   inb = (const u16*)in_;
  float* outf = (float*)out_;
  u16*   outb = (u16*)out_;

  __shared__ float in_lds[8][34][18];   // 19584 B
  __shared__ float w_lds[8][9][32];     // 9216 B
  int bid = blockIdx.x;
  int ocg = bid & 3;
  int bx  = (bid >> 2) & 7;
  int byy = (bid >> 5) & 3;
  int b   = bid >> 7;
  int oc0 = ocg * 32;
  int x0 = bx * 16, y0 = byy * 32;
  int tid = threadIdx.x;
  int tx = tid & 15, ty = tid >> 4;   // ty 0..15

  float acc0[32], acc1[32];
#pragma unroll
  for (int i = 0; i < 32; i++) { acc0[i] = 0.f; acc1[i] = 0.f; }

  for (int cc = 0; cc < CC_; cc += 8) {
    __syncthreads();
    // stage input tile (8 ic x 34 x 18, halo=1)
    for (int idx = tid; idx < 8 * 34 * 18; idx += 256) {
      int ic = idx / 612; int r = idx % 612; int y = r / 18; int x = r % 18;
      int gy = y0 + y - 1, gx = x0 + x - 1;
      float v = 0.f;
      if (gy >= 0 && gy < HH_ && gx >= 0 && gx < WW_) {
        int g = ((b * CC_ + cc + ic) * HH_ + gy) * WW_ + gx;
        v = TIN_BF ? b2f(inb[g]) : inf[g];
      }
      in_lds[ic][y][x] = v;
    }
    // stage weights: [ic][tap][oc]
    for (int idx = tid; idx < 8 * 9 * 32; idx += 256) {
      int oc = idx & 31; int tap = (idx >> 5) % 9; int ic = idx / 288;
      w_lds[ic][tap][oc] = w[(oc0 + oc) * 1152 + (cc + ic) * 9 + tap];
    }
    __syncthreads();
#pragma unroll
    for (int ic = 0; ic < 8; ic++) {
      float av[9], bv[9];
#pragma unroll
      for (int dy = 0; dy < 3; dy++)
#pragma unroll
        for (int dx = 0; dx < 3; dx++) {
          av[dy * 3 + dx] = in_lds[ic][ty + dy][tx + dx];
          bv[dy * 3 + dx] = in_lds[ic][ty + 16 + dy][tx + dx];
        }
#pragma unroll
      for (int tap = 0; tap < 9; tap++) {
        const float4* wp = (const float4*)&w_lds[ic][tap][0];
        float a = av[tap], bb = bv[tap];
#pragma unroll
        for (int o4 = 0; o4 < 8; o4++) {
          float4 wv = wp[o4];
          acc0[o4 * 4 + 0] += a * wv.x;  acc0[o4 * 4 + 1] += a * wv.y;
          acc0[o4 * 4 + 2] += a * wv.z;  acc0[o4 * 4 + 3] += a * wv.w;
          acc1[o4 * 4 + 0] += bb * wv.x; acc1[o4 * 4 + 1] += bb * wv.y;
          acc1[o4 * 4 + 2] += bb * wv.z; acc1[o4 * 4 + 3] += bb * wv.w;
        }
      }
    }
  }
  int yA = y0 + ty, yB = y0 + ty + 16, xw = x0 + tx;
#pragma unroll
  for (int o = 0; o < 32; o++) {
    float bz = bias[oc0 + o];
    float r0 = acc0[o] + bz, r1 = acc1[o] + bz;
    if (ACT == 1) { r0 = 1.f / (1.f + expf(-r0)); r1 = 1.f / (1.f + expf(-r1)); }
    int gA = ((b * CC_ + oc0 + o) * HH_ + yA) * WW_ + xw;
    int gB = ((b * CC_ + oc0 + o) * HH_ + yB) * WW_ + xw;
    if (TOUT_BF) { outb[gA] = f2b(r0); outb[gB] = f2b(r1); }
    else         { outf[gA] = r0;      outf[gB] = r1; }
  }
}

// ---------------------------------------------------------------------------
// InstanceNorm stats over bf16 plane: one block per (b,c) (1024 blocks).
// ---------------------------------------------------------------------------
__global__ __launch_bounds__(256) void in_stats_kernel(
    const u16* __restrict__ t, float* __restrict__ mean_o,
    float* __restrict__ rstd_o)
{
  int bc = blockIdx.x;
  const uint4* p = (const uint4*)(t + (size_t)bc * NPLANE);   // 8 bf16 / uint4
  float s = 0.f, sq = 0.f;
  for (int i = threadIdx.x; i < NPLANE / 8; i += 256) {
    uint4 u = p[i];
    u32 ws[4] = {u.x, u.y, u.z, u.w};
#pragma unroll
    for (int j = 0; j < 4; j++) {
      float a = b2f((u16)(ws[j] & 0xFFFF));
      float bb = b2f((u16)(ws[j] >> 16));
      s += a + bb; sq += a * a + bb * bb;
    }
  }
  __shared__ float ss[256], sqq[256];
  int tid = threadIdx.x;
  ss[tid] = s; sqq[tid] = sq;
  __syncthreads();
  for (int off = 128; off > 0; off >>= 1) {
    if (tid < off) { ss[tid] += ss[tid + off]; sqq[tid] += sqq[tid + off]; }
    __syncthreads();
  }
  if (tid == 0) {
    float m = ss[0] * (1.f / NPLANE);
    float var = sqq[0] * (1.f / NPLANE) - m * m;
    mean_o[bc] = m;
    rstd_o[bc] = rsqrtf(var + 1e-5f);
  }
}

// ---------------------------------------------------------------------------
// normalize + LeakyReLU(0.2), in place on bf16, 8 elems/thread.
// ---------------------------------------------------------------------------
__global__ __launch_bounds__(256) void norm_leaky_kernel(
    u16* __restrict__ a, const float* __restrict__ mean,
    const float* __restrict__ rstd)
{
  int idx = blockIdx.x * 256 + threadIdx.x;   // uint4 index (8 bf16)
  if (idx >= NTOT / 8) return;
  int bc = idx >> 11;   // 2048 uint4 per plane
  float m = mean[bc], r = rstd[bc];
  uint4 u = ((uint4*)a)[idx];
  u32 ws[4] = {u.x, u.y, u.z, u.w};
#pragma unroll
  for (int j = 0; j < 4; j++) {
    float lo = b2f((u16)(ws[j] & 0xFFFF));
    float hi = b2f((u16)(ws[j] >> 16));
    lo = (lo - m) * r; lo = lo >= 0.f ? lo : 0.2f * lo;
    hi = (hi - m) * r; hi = hi >= 0.f ? hi : 0.2f * hi;
    ws[j] = (u32)f2b(lo) | ((u32)f2b(hi) << 16);
  }
  u.x = ws[0]; u.y = ws[1]; u.z = ws[2]; u.w = ws[3];
  ((uint4*)a)[idx] = u;
}

// ---------------------------------------------------------------------------
// conv1x1 on xm = xn*mask (bf16 in, bf16 out), fp32 accum.
// block: 128 oc x 64 px; thread: 8 oc x 4 px.
// ---------------------------------------------------------------------------
__global__ __launch_bounds__(256) void conv1x1_kernel(
    const u16* __restrict__ xn, const u16* __restrict__ mask,
    const float* __restrict__ w, const float* __restrict__ bias,
    u16* __restrict__ out)
{
  __shared__ float x_lds[16][64];
  __shared__ float w_lds[16][128];
  int bid = blockIdx.x;              // 8 * 256
  int px0 = (bid & 255) * 64;
  int b = bid >> 8;
  int tid = threadIdx.x;
  int pxg = tid & 15, ocg = tid >> 4;
  float acc[8][4];
#pragma unroll
  for (int o = 0; o < 8; o++)
#pragma unroll
    for (int p = 0; p < 4; p++) acc[o][p] = 0.f;

  for (int cc = 0; cc < CC_; cc += 16) {
    __syncthreads();
    for (int idx = tid; idx < 16 * 64; idx += 256) {
      int ic = idx >> 6, p = idx & 63;
      int g = (b * CC_ + cc + ic) * NPLANE + px0 + p;
      x_lds[ic][p] = b2f(xn[g]) * b2f(mask[g]);
    }
    for (int idx = tid; idx < 16 * 128; idx += 256) {
      int ic = idx >> 7, oc = idx & 127;
      w_lds[ic][oc] = w[oc * CC_ + cc + ic];
    }
    __syncthreads();
#pragma unroll
    for (int ic = 0; ic < 16; ic++) {
      float4 xv = *(const float4*)&x_lds[ic][pxg * 4];
      float4 w0 = *(const float4*)&w_lds[ic][ocg * 8];
      float4 w1 = *(const float4*)&w_lds[ic][ocg * 8 + 4];
      float xs[4] = {xv.x, xv.y, xv.z, xv.w};
      float wz[8] = {w0.x, w0.y, w0.z, w0.w, w1.x, w1.y, w1.z, w1.w};
#pragma unroll
      for (int o = 0; o < 8; o++)
#pragma unroll
        for (int p = 0; p < 4; p++) acc[o][p] += wz[o] * xs[p];
    }
  }
#pragma unroll
  for (int o = 0; o < 8; o++) {
    float bz = bias[ocg * 8 + o];
    int g = (b * CC_ + ocg * 8 + o) * NPLANE + px0 + pxg * 4;
    u16 r[4];
#pragma unroll
    for (int p = 0; p < 4; p++) r[p] = f2b(acc[o][p] + bz);
    *(ushort4*)&out[g] = *(ushort4*)r;
  }
}

// ---------------------------------------------------------------------------
// attention + final combine. block: 64 px (one row segment) x 4 c-groups.
// out1 lives in d_out (f32); read-then-overwrite per thread.
// Border k/v = bias (pad applied BEFORE the 1x1 conv in the reference).
// ---------------------------------------------------------------------------
__global__ __launch_bounds__(256) void attn_final_kernel(
    const float* __restrict__ x, const u16* __restrict__ mask,
    const u16* __restrict__ q, const u16* __restrict__ k,
    const u16* __restrict__ v, const float* __restrict__ kb,
    const float* __restrict__ vb, float* __restrict__ out)
{
  __shared__ float s_part[4][64][9];
  __shared__ float s_attn[64][9];
  int bid = blockIdx.x;              // 8*128*2
  int w0 = (bid & 1) * 64;
  int h = (bid >> 1) & 127;
  int b = bid >> 8;
  int tid = threadIdx.x;
  int px = tid & 63, cg = tid >> 6;
  int wI = w0 + px;

  float sims[9];
#pragma unroll
  for (int t = 0; t < 9; t++) sims[t] = 0.f;

  for (int ci = 0; ci < 32; ci++) {
    int c = cg * 32 + ci;
    int base = ((b * CC_ + c) * HH_ + h) * WW_ + wI;
    float qv = b2f(q[base]);
    float kbv = kb[c];
#pragma unroll
    for (int t = 0; t < 9; t++) {
      int di = t / 3 - 1, dj = t % 3 - 1;
      int hh = h + di, ww = wI + dj;
      float kv = (hh >= 0 && hh < HH_ && ww >= 0 && ww < WW_)
                 ? b2f(k[((b * CC_ + c) * HH_ + hh) * WW_ + ww]) : kbv;
      sims[t] += qv * kv;
    }
  }
#pragma unroll
  for (int t = 0; t < 9; t++) s_part[cg][px][t] = sims[t];
  __syncthreads();
  if (tid < 64) {
    float sv[9];
#pragma unroll
    for (int t = 0; t < 9; t++)
      sv[t] = s_part[0][tid][t] + s_part[1][tid][t] + s_part[2][tid][t] +
              s_part[3][tid][t];
    float m = sv[0];
#pragma unroll
    for (int t = 1; t < 9; t++) m = fmaxf(m, sv[t]);
    float e[9], ssum = 0.f;
#pragma unroll
    for (int t = 0; t < 9; t++) { e[t] = expf(sv[t] - m); ssum += e[t]; }
    float inv = 1.f / ssum;
#pragma unroll
    for (int t = 0; t < 9; t++) s_attn[tid][t] = e[t] * inv;
  }
  __syncthreads();
  float at[9];
#pragma unroll
  for (int t = 0; t < 9; t++) at[t] = s_attn[px][t];

  for (int ci = 0; ci < 32; ci++) {
    int c = cg * 32 + ci;
    int base = ((b * CC_ + c) * HH_ + h) * WW_ + wI;
    float vbv = vb[c];
    float acc = 0.f;
#pragma unroll
    for (int t = 0; t < 9; t++) {
      int di = t / 3 - 1, dj = t % 3 - 1;
      int hh = h + di, ww = wI + dj;
      float vv = (hh >= 0 && hh < HH_ && ww >= 0 && ww < WW_)
                 ? b2f(v[((b * CC_ + c) * HH_ + hh) * WW_ + ww]) : vbv;
      acc += at[t] * vv;
    }
    float mk = b2f(mask[base]);
    float o1 = out[base];              // out1 staged in d_out
    float xv = x[base];
    out[base] = xv + o1 * mk + (1.f - mk) * acc;
  }
}

// ---------------------------------------------------------------------------
extern "C" void kernel_launch(void* const* d_in, const int* in_sizes, int n_in,
                              void* d_out, int out_size, void* d_ws, size_t ws_size,
                              hipStream_t stream) {
  const float* x       = (const float*)d_in[0];
  const float* conv1_w = (const float*)d_in[1];
  const float* conv1_b = (const float*)d_in[2];
  const float* conv2_w = (const float*)d_in[3];
  const float* conv2_b = (const float*)d_in[4];
  const float* mask_w  = (const float*)d_in[5];
  const float* mask_b  = (const float*)d_in[6];
  const float* q_w     = (const float*)d_in[7];
  const float* q_b     = (const float*)d_in[8];
  const float* k_w     = (const float*)d_in[9];
  const float* k_b     = (const float*)d_in[10];
  const float* v_w     = (const float*)d_in[11];
  const float* v_b     = (const float*)d_in[12];
  float* out = (float*)d_out;

  // Workspace: 5 bf16 tensors (32 MB each = 168 MB total) + stats.
  u16* A = (u16*)d_ws;               // conv1 out -> xn (in place)
  u16* M = A + NTOT;                 // mask
  u16* Q = M + NTOT;
  u16* K = Q + NTOT;
  u16* V = K + NTOT;
  float* MEAN = (float*)(V + NTOT);  // 1024 f32
  float* RSTD = MEAN + 1024;
  // out1 is staged in d_out (f32) and consumed in place by attn_final.

  // 1. conv1: f32 in -> bf16 A
  hipLaunchKernelGGL((conv3x3_kernel<0,0,1>), dim3(1024), dim3(256), 0, stream,
                     (const void*)x, conv1_w, conv1_b, (void*)A);
  // 2. IN stats
  hipLaunchKernelGGL(in_stats_kernel, dim3(1024), dim3(256), 0, stream,
                     A, MEAN, RSTD);
  // 3. normalize + leaky (in place, bf16)
  hipLaunchKernelGGL(norm_leaky_kernel, dim3(NTOT / 8 / 256), dim3(256), 0,
                     stream, A, MEAN, RSTD);
  // 4. out1 = conv2(xn): bf16 in -> f32 d_out
  hipLaunchKernelGGL((conv3x3_kernel<0,1,0>), dim3(1024), dim3(256), 0, stream,
                     (const void*)A, conv2_w, conv2_b, (void*)out);
  // 5. mask = sigmoid(conv_mask(xn)): bf16 -> bf16
  hipLaunchKernelGGL((conv3x3_kernel<1,1,1>), dim3(1024), dim3(256), 0, stream,
                     (const void*)A, mask_w, mask_b, (void*)M);
  // 6-8. q, k, v (1x1 on xn*mask)
  hipLaunchKernelGGL(conv1x1_kernel, dim3(2048), dim3(256), 0, stream,
                     A, M, q_w, q_b, Q);
  hipLaunchKernelGGL(conv1x1_kernel, dim3(2048), dim3(256), 0, stream,
                     A, M, k_w, k_b, K);
  hipLaunchKernelGGL(conv1x1_kernel, dim3(2048), dim3(256), 0, stream,
                     A, M, v_w, v_b, V);
  // 9. attention + final combine
  hipLaunchKernelGGL(attn_final_kernel, dim3(2048), dim3(256), 0, stream,
                     x, M, Q, K, V, k_b, v_b, out);
}

// Round 5
// 524.875 us; speedup vs baseline: 11.9531x; 11.9531x over previous
//
#include <hip/hip_runtime.h>
#include <hip/hip_bf16.h>
#include <math.h>

#define CC_ 128
#define HH_ 128
#define WW_ 128
#define BB_ 8
#define NPLANE 16384
#define NTOT 16777216

typedef unsigned short u16;
typedef unsigned int u32;
typedef __attribute__((ext_vector_type(8))) short bf16x8;
typedef __attribute__((ext_vector_type(4))) float f32x4;

__device__ __forceinline__ float b2f(u16 u) {
  u32 x = ((u32)u) << 16;
  return __builtin_bit_cast(float, x);
}
__device__ __forceinline__ u16 f2b(float f) {
  u32 x = __builtin_bit_cast(u32, f);
  return (u16)((x + 0x7FFFu + ((x >> 16) & 1u)) >> 16);   // RNE
}
__device__ __forceinline__ void unpack8(uint4 u, float* f) {
  u32 a0 = u.x, a1 = u.y, a2 = u.z, a3 = u.w;
  f[0] = b2f((u16)(a0 & 0xFFFF)); f[1] = b2f((u16)(a0 >> 16));
  f[2] = b2f((u16)(a1 & 0xFFFF)); f[3] = b2f((u16)(a1 >> 16));
  f[4] = b2f((u16)(a2 & 0xFFFF)); f[5] = b2f((u16)(a2 >> 16));
  f[6] = b2f((u16)(a3 & 0xFFFF)); f[7] = b2f((u16)(a3 >> 16));
}

// ---------------------------------------------------------------------------
// Weight repack: fp32 OIHW (3x3) / OI (1x1) -> bf16 MFMA-A layout [kk][oc][32]
// 3x3: kk = tap*4 + icc (36 chunks). 1x1: kk = icc (4 chunks).
// ---------------------------------------------------------------------------
__global__ __launch_bounds__(256) void wconv_kernel(
    const float* __restrict__ w3a, const float* __restrict__ w3b,
    const float* __restrict__ w3c, const float* __restrict__ w1a,
    const float* __restrict__ w1b, const float* __restrict__ w1c,
    u16* __restrict__ wb3, u16* __restrict__ wb1)
{
  int idx = blockIdx.x * 256 + threadIdx.x;
  if (idx < 3 * 147456) {
    int conv = idx / 147456, r = idx % 147456;
    int kk = r >> 12, oc = (r >> 5) & 127, ks = r & 31;
    int tap = kk >> 2, icc = kk & 3, ic = icc * 32 + ks;
    const float* w = conv == 0 ? w3a : (conv == 1 ? w3b : w3c);
    wb3[idx] = f2b(w[oc * 1152 + ic * 9 + tap]);
  } else {
    int j = idx - 3 * 147456;
    if (j < 3 * 16384) {
      int conv = j / 16384, r = j % 16384;
      int kk = r >> 12, oc = (r >> 5) & 127, ks = r & 31;
      int ic = kk * 32 + ks;
      const float* w = conv == 0 ? w1a : (conv == 1 ? w1b : w1c);
      wb1[j] = f2b(w[oc * 128 + ic]);
    }
  }
}

// ---------------------------------------------------------------------------
// x fp32 NCHW -> bf16 NHWC. block = (b, h, 64-px wseg).
// ---------------------------------------------------------------------------
__global__ __launch_bounds__(256) void transpose_kernel(
    const float* __restrict__ x, u16* __restrict__ xt)
{
  __shared__ float t[128 * 65];
  int bid = blockIdx.x;
  int ws = bid & 1, h = (bid >> 1) & 127, b = bid >> 8;
  int w0 = ws * 64, tid = threadIdx.x;
  for (int u = tid; u < 2048; u += 256) {
    int c = u >> 4, w4 = u & 15;
    float4 v = *(const float4*)&x[(((b * 128 + c) * 128 + h) << 7) + w0 + w4 * 4];
    t[c * 65 + w4 * 4 + 0] = v.x; t[c * 65 + w4 * 4 + 1] = v.y;
    t[c * 65 + w4 * 4 + 2] = v.z; t[c * 65 + w4 * 4 + 3] = v.w;
  }
  __syncthreads();
  for (int u = tid; u < 1024; u += 256) {
    int px = u >> 4, cu = u & 15;
    u16 o[8];
#pragma unroll
    for (int j = 0; j < 8; j++) o[j] = f2b(t[(cu * 8 + j) * 65 + px]);
    u32 p0 = (u32)o[0] | ((u32)o[1] << 16), p1 = (u32)o[2] | ((u32)o[3] << 16);
    u32 p2 = (u32)o[4] | ((u32)o[5] << 16), p3 = (u32)o[6] | ((u32)o[7] << 16);
    uint4 val; val.x = p0; val.y = p1; val.z = p2; val.w = p3;
    *(uint4*)&xt[((((b << 7) + h) << 7) + w0 + px) * 128 + cu * 8] = val;
  }
}

// ---------------------------------------------------------------------------
// conv3x3 via MFMA implicit GEMM. Input NHWC bf16. Block = (b, y, 64-px wseg),
// all 128 oc. LDS: 3 rows x 66 px x 128 ic bf16, XOR-swizzled.
// OUT_NCHW=0: NHWC bf16 out (mfma(A=w, B=x): lane holds 4 consecutive oc)
// OUT_NCHW=1: NCHW f32 out  (mfma(A=x, B=w): lane holds 4 consecutive px)
// ACT=1: sigmoid (NHWC mode only).
// ---------------------------------------------------------------------------
template<int ACT, int OUT_NCHW>
__global__ __launch_bounds__(256) void conv3_mfma_kernel(
    const u16* __restrict__ xin, const u16* __restrict__ wb,
    const float* __restrict__ bias, void* __restrict__ out_)
{
  __shared__ u16 lds[25344];   // 3*66*128 bf16 = 50688 B
  int bid = blockIdx.x;
  int ws = bid & 1, y = (bid >> 1) & 127, b = bid >> 8;
  int w0 = ws * 64, tid = threadIdx.x;

  for (int u = tid; u < 3168; u += 256) {     // 16B units: 3*66*16
    int r = u / 1056, rem = u % 1056;
    int px = rem >> 4, cu = rem & 15;
    int gy = y - 1 + r, gx = w0 - 1 + px;
    uint4 val; val.x = 0; val.y = 0; val.z = 0; val.w = 0;
    if (gy >= 0 && gy < 128 && gx >= 0 && gx < 128)
      val = *(const uint4*)&xin[((((b << 7) + gy) << 7) + gx) * 128 + cu * 8];
    int byte = (((r * 66 + px) << 8) + (cu << 4)) ^ ((px & 7) << 4);
    *(uint4*)((char*)lds + byte) = val;
  }
  __syncthreads();

  int wid = tid >> 6, l = tid & 63;
  int l15 = l & 15, l4 = l >> 4;
  f32x4 acc[2][4];
#pragma unroll
  for (int i = 0; i < 2; i++)
#pragma unroll
    for (int j = 0; j < 4; j++) { acc[i][j][0] = 0.f; acc[i][j][1] = 0.f; acc[i][j][2] = 0.f; acc[i][j][3] = 0.f; }

  const u16* wbaseA = wb + wid * 1024 + l15 * 32 + l4 * 8;
  for (int tap = 0; tap < 9; tap++) {
    int dy = tap / 3, dx = tap % 3;
    int rowoff = (dy * 66) << 8;
#pragma unroll
    for (int icc = 0; icc < 4; icc++) {
      int kk = tap * 4 + icc;
      const u16* wk = wbaseA + kk * 4096;
      bf16x8 a0 = *(const bf16x8*)wk;
      bf16x8 a1 = *(const bf16x8*)(wk + 512);
#pragma unroll
      for (int pb = 0; pb < 4; pb++) {
        int px = pb * 16 + l15 + dx;
        int byte = ((rowoff + (px << 8)) + (icc << 6) + (l4 << 4)) ^ ((px & 7) << 4);
        bf16x8 bf = *(const bf16x8*)((const char*)lds + byte);
        if (OUT_NCHW) {
          acc[0][pb] = __builtin_amdgcn_mfma_f32_16x16x32_bf16(bf, a0, acc[0][pb], 0, 0, 0);
          acc[1][pb] = __builtin_amdgcn_mfma_f32_16x16x32_bf16(bf, a1, acc[1][pb], 0, 0, 0);
        } else {
          acc[0][pb] = __builtin_amdgcn_mfma_f32_16x16x32_bf16(a0, bf, acc[0][pb], 0, 0, 0);
          acc[1][pb] = __builtin_amdgcn_mfma_f32_16x16x32_bf16(a1, bf, acc[1][pb], 0, 0, 0);
        }
      }
    }
  }

  if (OUT_NCHW) {
    float* outf = (float*)out_;
#pragma unroll
    for (int ob2 = 0; ob2 < 2; ob2++) {
      int oc = (wid * 2 + ob2) * 16 + l15;
      float bz = bias[oc];
#pragma unroll
      for (int pb = 0; pb < 4; pb++) {
        int px0 = pb * 16 + (l4 << 2);
        float4 v;
        v.x = acc[ob2][pb][0] + bz; v.y = acc[ob2][pb][1] + bz;
        v.z = acc[ob2][pb][2] + bz; v.w = acc[ob2][pb][3] + bz;
        *(float4*)&outf[(((b << 7) + oc) << 14) + (y << 7) + w0 + px0] = v;
      }
    }
  } else {
    u16* outb = (u16*)out_;
#pragma unroll
    for (int ob2 = 0; ob2 < 2; ob2++) {
      int oc0 = (wid * 2 + ob2) * 16 + (l4 << 2);
#pragma unroll
      for (int pb = 0; pb < 4; pb++) {
        int px = pb * 16 + l15;
        int pix = (b << 14) + (y << 7) + w0 + px;
        u16 o[4];
#pragma unroll
        for (int r = 0; r < 4; r++) {
          float v = acc[ob2][pb][r] + bias[oc0 + r];
          if (ACT == 1) v = 1.f / (1.f + expf(-v));
          o[r] = f2b(v);
        }
        u32 lo = (u32)o[0] | ((u32)o[1] << 16), hi = (u32)o[2] | ((u32)o[3] << 16);
        uint2 val; val.x = lo; val.y = hi;
        *(uint2*)&outb[pix * 128 + oc0] = val;
      }
    }
  }
}

// ---------------------------------------------------------------------------
// stats pipeline (NHWC): zero -> atomic partial sums -> finalize -> norm+leaky
// ---------------------------------------------------------------------------
__global__ __launch_bounds__(256) void zero_stats_kernel(float* __restrict__ s)
{
  for (int u = threadIdx.x; u < 4096; u += 256) s[u] = 0.f;
}

__global__ __launch_bounds__(256) void stats_kernel(
    const u16* __restrict__ a, float* __restrict__ SUM, float* __restrict__ SQS)
{
  int bid = blockIdx.x;                 // 2048 blocks = 64 px each
  size_t base = (size_t)bid * 8192;
  int tid = threadIdx.x, c = tid & 127;
  float s = 0.f, sq = 0.f;
#pragma unroll 4
  for (int k = 0; k < 32; k++) {
    float v = b2f(a[base + k * 256 + tid]);
    s += v; sq += v * v;
  }
  __shared__ float ls[256], lq[256];
  ls[tid] = s; lq[tid] = sq;
  __syncthreads();
  if (tid < 128) {
    s = ls[tid] + ls[tid + 128];
    sq = lq[tid] + lq[tid + 128];
    int b = bid >> 8;
    atomicAdd(&SUM[b * 128 + c], s);
    atomicAdd(&SQS[b * 128 + c], sq);
  }
}

__global__ __launch_bounds__(256) void finalize_stats_kernel(
    const float* __restrict__ SUM, const float* __restrict__ SQS,
    float* __restrict__ MEAN, float* __restrict__ RSTD)
{
  int i = blockIdx.x * 256 + threadIdx.x;
  if (i < 1024) {
    float m = SUM[i] * (1.f / 16384.f);
    MEAN[i] = m;
    RSTD[i] = rsqrtf(SQS[i] * (1.f / 16384.f) - m * m + 1e-5f);
  }
}

__global__ __launch_bounds__(256) void norm_kernel(
    u16* __restrict__ a, const float* __restrict__ MEAN,
    const float* __restrict__ RSTD)
{
  int idx = blockIdx.x * 256 + threadIdx.x;   // 16B units, NTOT/8 total
  int p = idx >> 4, cu = idx & 15, bb = p >> 14;
  const float* Mn = MEAN + bb * 128 + cu * 8;
  const float* Rs = RSTD + bb * 128 + cu * 8;
  uint4 u = *(uint4*)&a[(size_t)idx * 8];
  float f[8];
  unpack8(u, f);
  u16 o[8];
#pragma unroll
  for (int j = 0; j < 8; j++) {
    float v = (f[j] - Mn[j]) * Rs[j];
    v = v >= 0.f ? v : 0.2f * v;
    o[j] = f2b(v);
  }
  u32 p0 = (u32)o[0] | ((u32)o[1] << 16), p1 = (u32)o[2] | ((u32)o[3] << 16);
  u32 p2 = (u32)o[4] | ((u32)o[5] << 16), p3 = (u32)o[6] | ((u32)o[7] << 16);
  uint4 val; val.x = p0; val.y = p1; val.z = p2; val.w = p3;
  *(uint4*)&a[(size_t)idx * 8] = val;
}

// ---------------------------------------------------------------------------
// fused q/k/v 1x1 convs via MFMA. xm = xn*mask staged once (NHWC, swizzled).
// ---------------------------------------------------------------------------
__global__ __launch_bounds__(256) void qkv_mfma_kernel(
    const u16* __restrict__ A, const u16* __restrict__ Mb,
    const u16* __restrict__ wb1,
    const float* __restrict__ qb, const float* __restrict__ kb,
    const float* __restrict__ vb,
    u16* __restrict__ Qo, u16* __restrict__ Ko, u16* __restrict__ Vo)
{
  __shared__ u16 lds[8192];   // 64 px x 128 c
  int bid = blockIdx.x;
  int p0 = bid * 64, tid = threadIdx.x;
  for (int u = tid; u < 1024; u += 256) {
    int px = u >> 4, cu = u & 15;
    int g = (p0 + px) * 128 + cu * 8;
    float xf[8], mf[8];
    unpack8(*(const uint4*)&A[g], xf);
    unpack8(*(const uint4*)&Mb[g], mf);
    u16 o[8];
#pragma unroll
    for (int j = 0; j < 8; j++) o[j] = f2b(xf[j] * mf[j]);
    u32 q0 = (u32)o[0] | ((u32)o[1] << 16), q1 = (u32)o[2] | ((u32)o[3] << 16);
    u32 q2 = (u32)o[4] | ((u32)o[5] << 16), q3 = (u32)o[6] | ((u32)o[7] << 16);
    uint4 val; val.x = q0; val.y = q1; val.z = q2; val.w = q3;
    int byte = (((px << 8) + (cu << 4))) ^ ((px & 7) << 4);
    *(uint4*)((char*)lds + byte) = val;
  }
  __syncthreads();

  int wid = tid >> 6, l = tid & 63;
  int l15 = l & 15, l4 = l >> 4;
  for (int conv = 0; conv < 3; conv++) {
    const u16* wb = wb1 + conv * 16384;
    const float* bias = conv == 0 ? qb : (conv == 1 ? kb : vb);
    u16* out = conv == 0 ? Qo : (conv == 1 ? Ko : Vo);
    f32x4 acc[2][4];
#pragma unroll
    for (int i = 0; i < 2; i++)
#pragma unroll
      for (int j = 0; j < 4; j++) { acc[i][j][0] = 0.f; acc[i][j][1] = 0.f; acc[i][j][2] = 0.f; acc[i][j][3] = 0.f; }
#pragma unroll
    for (int kk = 0; kk < 4; kk++) {
      const u16* wk = wb + kk * 4096 + wid * 1024 + l15 * 32 + l4 * 8;
      bf16x8 a0 = *(const bf16x8*)wk;
      bf16x8 a1 = *(const bf16x8*)(wk + 512);
#pragma unroll
      for (int pb = 0; pb < 4; pb++) {
        int px = pb * 16 + l15;
        int byte = (((px << 8) + (kk << 6) + (l4 << 4))) ^ ((px & 7) << 4);
        bf16x8 bf = *(const bf16x8*)((const char*)lds + byte);
        acc[0][pb] = __builtin_amdgcn_mfma_f32_16x16x32_bf16(a0, bf, acc[0][pb], 0, 0, 0);
        acc[1][pb] = __builtin_amdgcn_mfma_f32_16x16x32_bf16(a1, bf, acc[1][pb], 0, 0, 0);
      }
    }
#pragma unroll
    for (int ob2 = 0; ob2 < 2; ob2++) {
      int oc0 = (wid * 2 + ob2) * 16 + (l4 << 2);
#pragma unroll
      for (int pb = 0; pb < 4; pb++) {
        int px = pb * 16 + l15;
        u16 o[4];
#pragma unroll
        for (int r = 0; r < 4; r++) o[r] = f2b(acc[ob2][pb][r] + bias[oc0 + r]);
        u32 lo = (u32)o[0] | ((u32)o[1] << 16), hi = (u32)o[2] | ((u32)o[3] << 16);
        uint2 val; val.x = lo; val.y = hi;
        *(uint2*)&out[(p0 + px) * 128 + oc0] = val;
      }
    }
  }
}

// ---------------------------------------------------------------------------
// attention + final combine. NHWC bf16 q/k/v/mask; x, out1(d_out), out NCHW f32.
// thread: px = tid>>2 (64), cg = tid&3 (32 ch each).
// ---------------------------------------------------------------------------
__global__ __launch_bounds__(256) void attn_final_kernel(
    const float* __restrict__ x, const u16* __restrict__ msk,
    const u16* __restrict__ q, const u16* __restrict__ k,
    const u16* __restrict__ v, const float* __restrict__ kb,
    const float* __restrict__ vb, float* __restrict__ out)
{
  __shared__ float s_part[64][4][9];
  __shared__ float s_attn[64][9];
  int bid = blockIdx.x;
  int ws = bid & 1, h = (bid >> 1) & 127, b = bid >> 8;
  int w0 = ws * 64, tid = threadIdx.x;
  int px = tid >> 2, cg = tid & 3, c0 = cg * 32;
  int wI = w0 + px;
  int pix = (b << 14) + (h << 7) + wI;

  float qv[32];
#pragma unroll
  for (int u = 0; u < 4; u++)
    unpack8(*(const uint4*)&q[pix * 128 + c0 + u * 8], &qv[u * 8]);

  float sims[9];
#pragma unroll
  for (int t = 0; t < 9; t++) {
    int dy = t / 3 - 1, dx = t % 3 - 1;
    int hh = h + dy, ww = wI + dx;
    float s = 0.f;
    if (hh >= 0 && hh < 128 && ww >= 0 && ww < 128) {
      int kbase = (pix + dy * 128 + dx) * 128 + c0;
      float kv[8];
#pragma unroll
      for (int u = 0; u < 4; u++) {
        unpack8(*(const uint4*)&k[kbase + u * 8], kv);
#pragma unroll
        for (int j = 0; j < 8; j++) s += qv[u * 8 + j] * kv[j];
      }
    } else {
#pragma unroll
      for (int j = 0; j < 32; j++) s += qv[j] * kb[c0 + j];
    }
    sims[t] = s;
  }
#pragma unroll
  for (int t = 0; t < 9; t++) s_part[px][cg][t] = sims[t];
  __syncthreads();
  if (tid < 64) {
    float sv[9];
#pragma unroll
    for (int t = 0; t < 9; t++)
      sv[t] = s_part[tid][0][t] + s_part[tid][1][t] + s_part[tid][2][t] + s_part[tid][3][t];
    float m = sv[0];
#pragma unroll
    for (int t = 1; t < 9; t++) m = fmaxf(m, sv[t]);
    float e[9], ssum = 0.f;
#pragma unroll
    for (int t = 0; t < 9; t++) { e[t] = expf(sv[t] - m); ssum += e[t]; }
    float inv = 1.f / ssum;
#pragma unroll
    for (int t = 0; t < 9; t++) s_attn[tid][t] = e[t] * inv;
  }
  __syncthreads();
  float at[9];
#pragma unroll
  for (int t = 0; t < 9; t++) at[t] = s_attn[px][t];

  float acc[32];
#pragma unroll
  for (int j = 0; j < 32; j++) acc[j] = 0.f;
#pragma unroll
  for (int t = 0; t < 9; t++) {
    int dy = t / 3 - 1, dx = t % 3 - 1;
    int hh = h + dy, ww = wI + dx;
    if (hh >= 0 && hh < 128 && ww >= 0 && ww < 128) {
      int vbase = (pix + dy * 128 + dx) * 128 + c0;
      float vv[8];
#pragma unroll
      for (int u = 0; u < 4; u++) {
        unpack8(*(const uint4*)&v[vbase + u * 8], vv);
#pragma unroll
        for (int j = 0; j < 8; j++) acc[u * 8 + j] += at[t] * vv[j];
      }
    } else {
#pragma unroll
      for (int j = 0; j < 32; j++) acc[j] += at[t] * vb[c0 + j];
    }
  }

  float mk[32];
#pragma unroll
  for (int u = 0; u < 4; u++)
    unpack8(*(const uint4*)&msk[pix * 128 + c0 + u * 8], &mk[u * 8]);

#pragma unroll
  for (int j = 0; j < 32; j++) {
    int ga = (((b << 7) + c0 + j) << 14) + (h << 7) + wI;
    float o1 = out[ga];
    float xv = x[ga];
    out[ga] = xv + o1 * mk[j] + (1.f - mk[j]) * acc[j];
  }
}

// ---------------------------------------------------------------------------
extern "C" void kernel_launch(void* const* d_in, const int* in_sizes, int n_in,
                              void* d_out, int out_size, void* d_ws, size_t ws_size,
                              hipStream_t stream) {
  const float* x       = (const float*)d_in[0];
  const float* conv1_w = (const float*)d_in[1];
  const float* conv1_b = (const float*)d_in[2];
  const float* conv2_w = (const float*)d_in[3];
  const float* conv2_b = (const float*)d_in[4];
  const float* mask_w  = (const float*)d_in[5];
  const float* mask_b  = (const float*)d_in[6];
  const float* q_w     = (const float*)d_in[7];
  const float* q_b     = (const float*)d_in[8];
  const float* k_w     = (const float*)d_in[9];
  const float* k_b     = (const float*)d_in[10];
  const float* v_w     = (const float*)d_in[11];
  const float* v_b     = (const float*)d_in[12];
  float* out = (float*)d_out;

  // ws: A, M, Q, K, V (bf16 NHWC, 32 MB each; XT aliases Q), weights, stats.
  u16* A  = (u16*)d_ws;
  u16* Mb = A + NTOT;
  u16* Q  = Mb + NTOT;     // also XT (transposed x) before qkv runs
  u16* K  = Q + NTOT;
  u16* V  = K + NTOT;
  u16* WB3 = V + NTOT;                 // 3 * 147456
  u16* WB1 = WB3 + 3 * 147456;         // 3 * 16384
  float* SUM  = (float*)(WB1 + 3 * 16384);
  float* SQS  = SUM + 1024;
  float* MEAN = SQS + 1024;
  float* RSTD = MEAN + 1024;
  u16* XT = Q;

  // 1. weight repack
  hipLaunchKernelGGL(wconv_kernel, dim3(1920), dim3(256), 0, stream,
                     conv1_w, conv2_w, mask_w, q_w, k_w, v_w, WB3, WB1);
  // 2. x -> NHWC bf16
  hipLaunchKernelGGL(transpose_kernel, dim3(2048), dim3(256), 0, stream, x, XT);
  // 3. conv1 (NHWC out)
  hipLaunchKernelGGL((conv3_mfma_kernel<0, 0>), dim3(2048), dim3(256), 0, stream,
                     XT, WB3, conv1_b, (void*)A);
  // 4-7. InstanceNorm + LeakyReLU
  hipLaunchKernelGGL(zero_stats_kernel, dim3(1), dim3(256), 0, stream, SUM);
  hipLaunchKernelGGL(stats_kernel, dim3(2048), dim3(256), 0, stream, A, SUM, SQS);
  hipLaunchKernelGGL(finalize_stats_kernel, dim3(4), dim3(256), 0, stream,
                     SUM, SQS, MEAN, RSTD);
  hipLaunchKernelGGL(norm_kernel, dim3(NTOT / 8 / 256), dim3(256), 0, stream,
                     A, MEAN, RSTD);
  // 8. out1 = conv2(xn) -> d_out (NCHW f32)
  hipLaunchKernelGGL((conv3_mfma_kernel<0, 1>), dim3(2048), dim3(256), 0, stream,
                     A, WB3 + 147456, conv2_b, (void*)out);
  // 9. mask = sigmoid(conv_mask(xn)) -> NHWC bf16
  hipLaunchKernelGGL((conv3_mfma_kernel<1, 0>), dim3(2048), dim3(256), 0, stream,
                     A, WB3 + 2 * 147456, mask_b, (void*)Mb);
  // 10. q,k,v fused 1x1
  hipLaunchKernelGGL(qkv_mfma_kernel, dim3(2048), dim3(256), 0, stream,
                     A, Mb, WB1, q_b, k_b, v_b, Q, K, V);
  // 11. attention + final combine
  hipLaunchKernelGGL(attn_final_kernel, dim3(2048), dim3(256), 0, stream,
                     x, Mb, Q, K, V, k_b, v_b, out);
}

// Round 6
// 501.566 us; speedup vs baseline: 12.5086x; 1.0465x over previous
//
#include <hip/hip_runtime.h>
#include <hip/hip_bf16.h>
#include <math.h>

#define NTOT 16777216

typedef unsigned short u16;
typedef unsigned int u32;
typedef __attribute__((ext_vector_type(8))) short bf16x8;
typedef __attribute__((ext_vector_type(4))) float f32x4;

__device__ __forceinline__ float b2f(u16 u) {
  u32 x = ((u32)u) << 16;
  return __builtin_bit_cast(float, x);
}
__device__ __forceinline__ u16 f2b(float f) {
  u32 x = __builtin_bit_cast(u32, f);
  return (u16)((x + 0x7FFFu + ((x >> 16) & 1u)) >> 16);   // RNE
}
__device__ __forceinline__ void unpack8(uint4 u, float* f) {
  u32 a0 = u.x, a1 = u.y, a2 = u.z, a3 = u.w;
  f[0] = b2f((u16)(a0 & 0xFFFF)); f[1] = b2f((u16)(a0 >> 16));
  f[2] = b2f((u16)(a1 & 0xFFFF)); f[3] = b2f((u16)(a1 >> 16));
  f[4] = b2f((u16)(a2 & 0xFFFF)); f[5] = b2f((u16)(a2 >> 16));
  f[6] = b2f((u16)(a3 & 0xFFFF)); f[7] = b2f((u16)(a3 >> 16));
}
__device__ __forceinline__ uint4 pack8(const u16* o) {
  uint4 v;
  v.x = (u32)o[0] | ((u32)o[1] << 16);
  v.y = (u32)o[2] | ((u32)o[3] << 16);
  v.z = (u32)o[4] | ((u32)o[5] << 16);
  v.w = (u32)o[6] | ((u32)o[7] << 16);
  return v;
}

// ---------------------------------------------------------------------------
// Weight repack: fp32 OIHW (3x3) / OI (1x1) -> bf16 MFMA-A layout [kk][oc][32]
// ---------------------------------------------------------------------------
__global__ __launch_bounds__(256) void wconv_kernel(
    const float* __restrict__ w3a, const float* __restrict__ w3b,
    const float* __restrict__ w3c, const float* __restrict__ w1a,
    const float* __restrict__ w1b, const float* __restrict__ w1c,
    u16* __restrict__ wb3, u16* __restrict__ wb1)
{
  int idx = blockIdx.x * 256 + threadIdx.x;
  if (idx < 3 * 147456) {
    int conv = idx / 147456, r = idx % 147456;
    int kk = r >> 12, oc = (r >> 5) & 127, ks = r & 31;
    int tap = kk >> 2, icc = kk & 3, ic = icc * 32 + ks;
    const float* w = conv == 0 ? w3a : (conv == 1 ? w3b : w3c);
    wb3[idx] = f2b(w[oc * 1152 + ic * 9 + tap]);
  } else {
    int j = idx - 3 * 147456;
    if (j < 3 * 16384) {
      int conv = j / 16384, r = j % 16384;
      int kk = r >> 12, oc = (r >> 5) & 127, ks = r & 31;
      int ic = kk * 32 + ks;
      const float* w = conv == 0 ? w1a : (conv == 1 ? w1b : w1c);
      wb1[j] = f2b(w[oc * 128 + ic]);
    }
  }
}

// ---------------------------------------------------------------------------
// x fp32 NCHW -> bf16 NHWC
// ---------------------------------------------------------------------------
__global__ __launch_bounds__(256) void transpose_kernel(
    const float* __restrict__ x, u16* __restrict__ xt)
{
  __shared__ float t[128 * 65];
  int bid = blockIdx.x;
  int ws = bid & 1, h = (bid >> 1) & 127, b = bid >> 8;
  int w0 = ws * 64, tid = threadIdx.x;
  for (int u = tid; u < 2048; u += 256) {
    int c = u >> 4, w4 = u & 15;
    float4 v = *(const float4*)&x[(((b * 128 + c) * 128 + h) << 7) + w0 + w4 * 4];
    t[c * 65 + w4 * 4 + 0] = v.x; t[c * 65 + w4 * 4 + 1] = v.y;
    t[c * 65 + w4 * 4 + 2] = v.z; t[c * 65 + w4 * 4 + 3] = v.w;
  }
  __syncthreads();
  for (int u = tid; u < 1024; u += 256) {
    int px = u >> 4, cu = u & 15;
    u16 o[8];
#pragma unroll
    for (int j = 0; j < 8; j++) o[j] = f2b(t[(cu * 8 + j) * 65 + px]);
    *(uint4*)&xt[((((b << 7) + h) << 7) + w0 + px) * 128 + cu * 8] = pack8(o);
  }
}

// ---------------------------------------------------------------------------
// zero SUM/SQS (2048 f32)
// ---------------------------------------------------------------------------
__global__ __launch_bounds__(256) void zero_stats_kernel(float* __restrict__ s)
{
  for (int u = threadIdx.x; u < 2048; u += 256) s[u] = 0.f;
}

// ---------------------------------------------------------------------------
// conv1 (3x3 MFMA, NHWC bf16 out) + fused InstanceNorm partial stats.
// ---------------------------------------------------------------------------
__global__ __launch_bounds__(256) void conv1_mfma_kernel(
    const u16* __restrict__ xin, const u16* __restrict__ wb,
    const float* __restrict__ bias, u16* __restrict__ outA,
    float* __restrict__ SUM, float* __restrict__ SQS)
{
  __shared__ u16 lds[25344];   // 3*66*128 bf16
  int bid = blockIdx.x;
  int ws = bid & 1, y = (bid >> 1) & 127, b = bid >> 8;
  int w0 = ws * 64, tid = threadIdx.x;

  for (int u = tid; u < 3168; u += 256) {
    int r = u / 1056, rem = u % 1056;
    int px = rem >> 4, cu = rem & 15;
    int gy = y - 1 + r, gx = w0 - 1 + px;
    uint4 val; val.x = 0; val.y = 0; val.z = 0; val.w = 0;
    if (gy >= 0 && gy < 128 && gx >= 0 && gx < 128)
      val = *(const uint4*)&xin[((((b << 7) + gy) << 7) + gx) * 128 + cu * 8];
    int byte = (((r * 66 + px) << 8) + (cu << 4)) ^ ((px & 7) << 4);
    *(uint4*)((char*)lds + byte) = val;
  }
  __syncthreads();

  int wid = tid >> 6, l = tid & 63, l15 = l & 15, l4 = l >> 4;
  f32x4 acc[2][4];
#pragma unroll
  for (int i = 0; i < 2; i++)
#pragma unroll
    for (int j = 0; j < 4; j++) { acc[i][j][0]=0.f; acc[i][j][1]=0.f; acc[i][j][2]=0.f; acc[i][j][3]=0.f; }

  const u16* wbaseA = wb + wid * 1024 + l15 * 32 + l4 * 8;
  for (int tap = 0; tap < 9; tap++) {
    int dy = tap / 3, dx = tap % 3;
    int rowoff = (dy * 66) << 8;
#pragma unroll
    for (int icc = 0; icc < 4; icc++) {
      const u16* wk = wbaseA + (tap * 4 + icc) * 4096;
      bf16x8 a0 = *(const bf16x8*)wk;
      bf16x8 a1 = *(const bf16x8*)(wk + 512);
#pragma unroll
      for (int pb = 0; pb < 4; pb++) {
        int px = pb * 16 + l15 + dx;
        int byte = (rowoff + (px << 8) + (icc << 6) + (l4 << 4)) ^ ((px & 7) << 4);
        bf16x8 bf = *(const bf16x8*)((const char*)lds + byte);
        acc[0][pb] = __builtin_amdgcn_mfma_f32_16x16x32_bf16(a0, bf, acc[0][pb], 0, 0, 0);
        acc[1][pb] = __builtin_amdgcn_mfma_f32_16x16x32_bf16(a1, bf, acc[1][pb], 0, 0, 0);
      }
    }
  }

  float sv[2][4], sq[2][4];
#pragma unroll
  for (int i = 0; i < 2; i++)
#pragma unroll
    for (int r = 0; r < 4; r++) { sv[i][r] = 0.f; sq[i][r] = 0.f; }
  int pixbase = (b << 14) + (y << 7) + w0;
#pragma unroll
  for (int ob2 = 0; ob2 < 2; ob2++) {
    int oc0 = (wid * 2 + ob2) * 16 + (l4 << 2);
#pragma unroll
    for (int pb = 0; pb < 4; pb++) {
      int px = pb * 16 + l15;
      u16 o[4];
#pragma unroll
      for (int r = 0; r < 4; r++) {
        float v = acc[ob2][pb][r] + bias[oc0 + r];
        sv[ob2][r] += v; sq[ob2][r] += v * v;
        o[r] = f2b(v);
      }
      uint2 val; val.x = (u32)o[0] | ((u32)o[1] << 16); val.y = (u32)o[2] | ((u32)o[3] << 16);
      *(uint2*)&outA[(pixbase + px) * 128 + oc0] = val;
    }
  }
#pragma unroll
  for (int ob2 = 0; ob2 < 2; ob2++)
#pragma unroll
    for (int r = 0; r < 4; r++) {
      float a = sv[ob2][r], s2 = sq[ob2][r];
#pragma unroll
      for (int m = 1; m < 16; m <<= 1) { a += __shfl_xor(a, m); s2 += __shfl_xor(s2, m); }
      if (l15 == 0) {
        int oc = (wid * 2 + ob2) * 16 + (l4 << 2) + r;
        atomicAdd(&SUM[b * 128 + oc], a);
        atomicAdd(&SQS[b * 128 + oc], s2);
      }
    }
}

__global__ __launch_bounds__(256) void finalize_stats_kernel(
    const float* __restrict__ SUM, const float* __restrict__ SQS,
    float* __restrict__ MEAN, float* __restrict__ RSTD)
{
  int i = blockIdx.x * 256 + threadIdx.x;
  if (i < 1024) {
    float m = SUM[i] * (1.f / 16384.f);
    MEAN[i] = m;
    RSTD[i] = rsqrtf(SQS[i] * (1.f / 16384.f) - m * m + 1e-5f);
  }
}

// ---------------------------------------------------------------------------
// Fused: stage A (norm+leaky on load) -> conv2 (NCHW f32 -> d_out),
// mask conv (sigmoid -> Mb + LDS), xm = xn*mask (in-place LDS), q/k/v 1x1.
// ---------------------------------------------------------------------------
__global__ __launch_bounds__(256) void fused_cmq_kernel(
    const u16* __restrict__ A, const u16* __restrict__ wb2,
    const u16* __restrict__ wbm, const u16* __restrict__ wb1,
    const float* __restrict__ MEAN, const float* __restrict__ RSTD,
    const float* __restrict__ c2b, const float* __restrict__ mkb,
    const float* __restrict__ qb, const float* __restrict__ kb,
    const float* __restrict__ vb,
    float* __restrict__ out1, u16* __restrict__ Mb,
    u16* __restrict__ Q, u16* __restrict__ K, u16* __restrict__ V)
{
  __shared__ u16 lds[25344];           // 3*66*128 bf16; row-0 region reused for xm
  __shared__ float mnorm[128], rnorm[128];
  int bid = blockIdx.x;
  int ws = bid & 1, y = (bid >> 1) & 127, b = bid >> 8;
  int w0 = ws * 64, tid = threadIdx.x;

  if (tid < 128) { mnorm[tid] = MEAN[b * 128 + tid]; rnorm[tid] = RSTD[b * 128 + tid]; }
  __syncthreads();

  for (int u = tid; u < 3168; u += 256) {
    int r = u / 1056, rem = u % 1056;
    int px = rem >> 4, cu = rem & 15;
    int gy = y - 1 + r, gx = w0 - 1 + px;
    uint4 val; val.x = 0; val.y = 0; val.z = 0; val.w = 0;
    if (gy >= 0 && gy < 128 && gx >= 0 && gx < 128) {
      uint4 raw = *(const uint4*)&A[((((b << 7) + gy) << 7) + gx) * 128 + cu * 8];
      float f[8]; unpack8(raw, f);
      u16 o[8];
#pragma unroll
      for (int j = 0; j < 8; j++) {
        float v = (f[j] - mnorm[cu * 8 + j]) * rnorm[cu * 8 + j];
        v = v >= 0.f ? v : 0.2f * v;
        o[j] = f2b(v);
      }
      val = pack8(o);
    }
    int byte = (((r * 66 + px) << 8) + (cu << 4)) ^ ((px & 7) << 4);
    *(uint4*)((char*)lds + byte) = val;
  }
  __syncthreads();

  int wid = tid >> 6, l = tid & 63, l15 = l & 15, l4 = l >> 4;
  int pixbase = (b << 14) + (y << 7) + w0;

  // ---- conv2: NCHW f32 out (mfma(B=x, A=w): lane holds 4 consecutive px) ----
  {
    f32x4 acc[2][4];
#pragma unroll
    for (int i = 0; i < 2; i++)
#pragma unroll
      for (int j = 0; j < 4; j++) { acc[i][j][0]=0.f; acc[i][j][1]=0.f; acc[i][j][2]=0.f; acc[i][j][3]=0.f; }
    const u16* wbaseA = wb2 + wid * 1024 + l15 * 32 + l4 * 8;
    for (int tap = 0; tap < 9; tap++) {
      int dy = tap / 3, dx = tap % 3;
      int rowoff = (dy * 66) << 8;
#pragma unroll
      for (int icc = 0; icc < 4; icc++) {
        const u16* wk = wbaseA + (tap * 4 + icc) * 4096;
        bf16x8 a0 = *(const bf16x8*)wk;
        bf16x8 a1 = *(const bf16x8*)(wk + 512);
#pragma unroll
        for (int pb = 0; pb < 4; pb++) {
          int px = pb * 16 + l15 + dx;
          int byte = (rowoff + (px << 8) + (icc << 6) + (l4 << 4)) ^ ((px & 7) << 4);
          bf16x8 bf = *(const bf16x8*)((const char*)lds + byte);
          acc[0][pb] = __builtin_amdgcn_mfma_f32_16x16x32_bf16(bf, a0, acc[0][pb], 0, 0, 0);
          acc[1][pb] = __builtin_amdgcn_mfma_f32_16x16x32_bf16(bf, a1, acc[1][pb], 0, 0, 0);
        }
      }
    }
#pragma unroll
    for (int ob2 = 0; ob2 < 2; ob2++) {
      int oc = (wid * 2 + ob2) * 16 + l15;
      float bz = c2b[oc];
#pragma unroll
      for (int pb = 0; pb < 4; pb++) {
        int px0 = pb * 16 + (l4 << 2);
        float4 v;
        v.x = acc[ob2][pb][0] + bz; v.y = acc[ob2][pb][1] + bz;
        v.z = acc[ob2][pb][2] + bz; v.w = acc[ob2][pb][3] + bz;
        *(float4*)&out1[(((b << 7) + oc) << 14) + (y << 7) + w0 + px0] = v;
      }
    }
  }

  // ---- mask conv (NHWC mode), keep acc in regs ----
  f32x4 macc[2][4];
#pragma unroll
  for (int i = 0; i < 2; i++)
#pragma unroll
    for (int j = 0; j < 4; j++) { macc[i][j][0]=0.f; macc[i][j][1]=0.f; macc[i][j][2]=0.f; macc[i][j][3]=0.f; }
  {
    const u16* wbaseA = wbm + wid * 1024 + l15 * 32 + l4 * 8;
    for (int tap = 0; tap < 9; tap++) {
      int dy = tap / 3, dx = tap % 3;
      int rowoff = (dy * 66) << 8;
#pragma unroll
      for (int icc = 0; icc < 4; icc++) {
        const u16* wk = wbaseA + (tap * 4 + icc) * 4096;
        bf16x8 a0 = *(const bf16x8*)wk;
        bf16x8 a1 = *(const bf16x8*)(wk + 512);
#pragma unroll
        for (int pb = 0; pb < 4; pb++) {
          int px = pb * 16 + l15 + dx;
          int byte = (rowoff + (px << 8) + (icc << 6) + (l4 << 4)) ^ ((px & 7) << 4);
          bf16x8 bf = *(const bf16x8*)((const char*)lds + byte);
          macc[0][pb] = __builtin_amdgcn_mfma_f32_16x16x32_bf16(a0, bf, macc[0][pb], 0, 0, 0);
          macc[1][pb] = __builtin_amdgcn_mfma_f32_16x16x32_bf16(a1, bf, macc[1][pb], 0, 0, 0);
        }
      }
    }
  }
  __syncthreads();   // all tile reads done; row-0 region may be overwritten

  // ---- mask epilogue: sigmoid -> global Mb + LDS row-0 region [px][c] ----
#pragma unroll
  for (int ob2 = 0; ob2 < 2; ob2++) {
    int oc0 = (wid * 2 + ob2) * 16 + (l4 << 2);
#pragma unroll
    for (int pb = 0; pb < 4; pb++) {
      int px = pb * 16 + l15;
      u16 o[4];
#pragma unroll
      for (int r = 0; r < 4; r++) {
        float v = macc[ob2][pb][r] + mkb[oc0 + r];
        v = 1.f / (1.f + expf(-v));
        o[r] = f2b(v);
      }
      uint2 val; val.x = (u32)o[0] | ((u32)o[1] << 16); val.y = (u32)o[2] | ((u32)o[3] << 16);
      *(uint2*)&Mb[(pixbase + px) * 128 + oc0] = val;
      int byte = ((px << 8) + (oc0 << 1)) ^ ((px & 7) << 4);
      *(uint2*)((char*)lds + byte) = val;
    }
  }
  __syncthreads();

  // ---- xm = xn(center row) * mask, in place in row-0 region ----
  for (int u = tid; u < 1024; u += 256) {
    int px = u >> 4, cu = u & 15;
    int mb_ = ((px << 8) + (cu << 4)) ^ ((px & 7) << 4);
    int xb_ = (((66 + px + 1) << 8) + (cu << 4)) ^ (((px + 1) & 7) << 4);
    uint4 mv = *(uint4*)((char*)lds + mb_);
    uint4 xv = *(uint4*)((char*)lds + xb_);
    float mf[8], xf[8];
    unpack8(mv, mf); unpack8(xv, xf);
    u16 o[8];
#pragma unroll
    for (int j = 0; j < 8; j++) o[j] = f2b(mf[j] * xf[j]);
    *(uint4*)((char*)lds + mb_) = pack8(o);
  }
  __syncthreads();

  // ---- q/k/v 1x1 convs on xm ----
  for (int conv = 0; conv < 3; conv++) {
    const u16* wb = wb1 + conv * 16384;
    const float* bias = conv == 0 ? qb : (conv == 1 ? kb : vb);
    u16* out = conv == 0 ? Q : (conv == 1 ? K : V);
    f32x4 acc[2][4];
#pragma unroll
    for (int i = 0; i < 2; i++)
#pragma unroll
      for (int j = 0; j < 4; j++) { acc[i][j][0]=0.f; acc[i][j][1]=0.f; acc[i][j][2]=0.f; acc[i][j][3]=0.f; }
#pragma unroll
    for (int kk = 0; kk < 4; kk++) {
      const u16* wk = wb + kk * 4096 + wid * 1024 + l15 * 32 + l4 * 8;
      bf16x8 a0 = *(const bf16x8*)wk;
      bf16x8 a1 = *(const bf16x8*)(wk + 512);
#pragma unroll
      for (int pb = 0; pb < 4; pb++) {
        int px = pb * 16 + l15;
        int byte = ((px << 8) + (kk << 6) + (l4 << 4)) ^ ((px & 7) << 4);
        bf16x8 bf = *(const bf16x8*)((const char*)lds + byte);
        acc[0][pb] = __builtin_amdgcn_mfma_f32_16x16x32_bf16(a0, bf, acc[0][pb], 0, 0, 0);
        acc[1][pb] = __builtin_amdgcn_mfma_f32_16x16x32_bf16(a1, bf, acc[1][pb], 0, 0, 0);
      }
    }
#pragma unroll
    for (int ob2 = 0; ob2 < 2; ob2++) {
      int oc0 = (wid * 2 + ob2) * 16 + (l4 << 2);
#pragma unroll
      for (int pb = 0; pb < 4; pb++) {
        int px = pb * 16 + l15;
        u16 o[4];
#pragma unroll
        for (int r = 0; r < 4; r++) o[r] = f2b(acc[ob2][pb][r] + bias[oc0 + r]);
        uint2 val; val.x = (u32)o[0] | ((u32)o[1] << 16); val.y = (u32)o[2] | ((u32)o[3] << 16);
        *(uint2*)&out[(pixbase + px) * 128 + oc0] = val;
      }
    }
  }
}

// ---------------------------------------------------------------------------
// attention + final combine, two-phase.
// Phase A (channel-fast): sims/softmax/PV; out2+mask -> LDS [c][px].
// Phase B (px-fast): coalesced NCHW combine.
// ---------------------------------------------------------------------------
__global__ __launch_bounds__(256) void attn_final_kernel(
    const float* __restrict__ x, const u16* __restrict__ msk,
    const u16* __restrict__ q, const u16* __restrict__ k,
    const u16* __restrict__ v, const float* __restrict__ kb,
    const float* __restrict__ vb, float* __restrict__ out)
{
  __shared__ float s_part[64][4][9];   // 9216
  __shared__ float s_attn[64][9];      // 2304
  __shared__ u16 o2lds[128][66];       // 16896
  __shared__ u16 mklds[128][66];       // 16896
  int bid = blockIdx.x;
  int ws = bid & 1, h = (bid >> 1) & 127, b = bid >> 8;
  int w0 = ws * 64, tid = threadIdx.x;
  int px = tid >> 2, cg = tid & 3, c0 = cg * 32;
  int wI = w0 + px;
  int pix = (b << 14) + (h << 7) + wI;

  // stash mask into LDS (raw bf16)
#pragma unroll
  for (int u2 = 0; u2 < 4; u2++) {
    uint4 mu = *(const uint4*)&msk[pix * 128 + c0 + u2 * 8];
    u32 ms[4] = {mu.x, mu.y, mu.z, mu.w};
#pragma unroll
    for (int j2 = 0; j2 < 4; j2++) {
      mklds[c0 + u2 * 8 + j2 * 2][px]     = (u16)(ms[j2] & 0xFFFF);
      mklds[c0 + u2 * 8 + j2 * 2 + 1][px] = (u16)(ms[j2] >> 16);
    }
  }

  float qv[32];
#pragma unroll
  for (int u = 0; u < 4; u++)
    unpack8(*(const uint4*)&q[pix * 128 + c0 + u * 8], &qv[u * 8]);

  float sims[9];
#pragma unroll
  for (int t = 0; t < 9; t++) {
    int dy = t / 3 - 1, dx = t % 3 - 1;
    int hh = h + dy, ww = wI + dx;
    float s = 0.f;
    if (hh >= 0 && hh < 128 && ww >= 0 && ww < 128) {
      int kbase = (pix + dy * 128 + dx) * 128 + c0;
      float kv[8];
#pragma unroll
      for (int u = 0; u < 4; u++) {
        unpack8(*(const uint4*)&k[kbase + u * 8], kv);
#pragma unroll
        for (int j = 0; j < 8; j++) s += qv[u * 8 + j] * kv[j];
      }
    } else {
#pragma unroll
      for (int j = 0; j < 32; j++) s += qv[j] * kb[c0 + j];
    }
    sims[t] = s;
  }
#pragma unroll
  for (int t = 0; t < 9; t++) s_part[px][cg][t] = sims[t];
  __syncthreads();
  if (tid < 64) {
    float sv[9];
#pragma unroll
    for (int t = 0; t < 9; t++)
      sv[t] = s_part[tid][0][t] + s_part[tid][1][t] + s_part[tid][2][t] + s_part[tid][3][t];
    float m = sv[0];
#pragma unroll
    for (int t = 1; t < 9; t++) m = fmaxf(m, sv[t]);
    float e[9], ssum = 0.f;
#pragma unroll
    for (int t = 0; t < 9; t++) { e[t] = expf(sv[t] - m); ssum += e[t]; }
    float inv = 1.f / ssum;
#pragma unroll
    for (int t = 0; t < 9; t++) s_attn[tid][t] = e[t] * inv;
  }
  __syncthreads();
  float at[9];
#pragma unroll
  for (int t = 0; t < 9; t++) at[t] = s_attn[px][t];

  float acc[32];
#pragma unroll
  for (int j = 0; j < 32; j++) acc[j] = 0.f;
#pragma unroll
  for (int t = 0; t < 9; t++) {
    int dy = t / 3 - 1, dx = t % 3 - 1;
    int hh = h + dy, ww = wI + dx;
    if (hh >= 0 && hh < 128 && ww >= 0 && ww < 128) {
      int vbase = (pix + dy * 128 + dx) * 128 + c0;
      float vv[8];
#pragma unroll
      for (int u = 0; u < 4; u++) {
        unpack8(*(const uint4*)&v[vbase + u * 8], vv);
#pragma unroll
        for (int j = 0; j < 8; j++) acc[u * 8 + j] += at[t] * vv[j];
      }
    } else {
#pragma unroll
      for (int j = 0; j < 32; j++) acc[j] += at[t] * vb[c0 + j];
    }
  }
#pragma unroll
  for (int j = 0; j < 32; j++) o2lds[c0 + j][px] = f2b(acc[j]);
  __syncthreads();

  // Phase B: coalesced NCHW combine (2048 float4 units)
#pragma unroll
  for (int it = 0; it < 8; it++) {
    int u = it * 256 + tid;
    int c = u >> 4, p4 = (u & 15) << 2;
    int ga = (((b << 7) + c) << 14) + (h << 7) + w0 + p4;
    float4 xv = *(const float4*)&x[ga];
    float4 o1 = *(const float4*)&out[ga];
    u32 oa = *(u32*)&o2lds[c][p4], ob = *(u32*)&o2lds[c][p4 + 2];
    u32 ma = *(u32*)&mklds[c][p4], mb2 = *(u32*)&mklds[c][p4 + 2];
    float o2v[4] = {b2f((u16)(oa & 0xFFFF)), b2f((u16)(oa >> 16)),
                    b2f((u16)(ob & 0xFFFF)), b2f((u16)(ob >> 16))};
    float mkv[4] = {b2f((u16)(ma & 0xFFFF)), b2f((u16)(ma >> 16)),
                    b2f((u16)(mb2 & 0xFFFF)), b2f((u16)(mb2 >> 16))};
    float4 r;
    r.x = xv.x + o1.x * mkv[0] + (1.f - mkv[0]) * o2v[0];
    r.y = xv.y + o1.y * mkv[1] + (1.f - mkv[1]) * o2v[1];
    r.z = xv.z + o1.z * mkv[2] + (1.f - mkv[2]) * o2v[2];
    r.w = xv.w + o1.w * mkv[3] + (1.f - mkv[3]) * o2v[3];
    *(float4*)&out[ga] = r;
  }
}

// ---------------------------------------------------------------------------
extern "C" void kernel_launch(void* const* d_in, const int* in_sizes, int n_in,
                              void* d_out, int out_size, void* d_ws, size_t ws_size,
                              hipStream_t stream) {
  const float* x       = (const float*)d_in[0];
  const float* conv1_w = (const float*)d_in[1];
  const float* conv1_b = (const float*)d_in[2];
  const float* conv2_w = (const float*)d_in[3];
  const float* conv2_b = (const float*)d_in[4];
  const float* mask_w  = (const float*)d_in[5];
  const float* mask_b  = (const float*)d_in[6];
  const float* q_w     = (const float*)d_in[7];
  const float* q_b     = (const float*)d_in[8];
  const float* k_w     = (const float*)d_in[9];
  const float* k_b     = (const float*)d_in[10];
  const float* v_w     = (const float*)d_in[11];
  const float* v_b     = (const float*)d_in[12];
  float* out = (float*)d_out;

  u16* A  = (u16*)d_ws;                // conv1 out (raw bf16 NHWC)
  u16* Mb = A + NTOT;                  // mask NHWC
  u16* Q  = Mb + NTOT;                 // XT alias before fused runs
  u16* K  = Q + NTOT;
  u16* V  = K + NTOT;
  u16* WB3 = V + NTOT;                 // 3 * 147456
  u16* WB1 = WB3 + 3 * 147456;         // 3 * 16384
  float* SUM  = (float*)(WB1 + 3 * 16384);
  float* SQS  = SUM + 1024;
  float* MEAN = SQS + 1024;
  float* RSTD = MEAN + 1024;
  u16* XT = Q;

  hipLaunchKernelGGL(wconv_kernel, dim3(1920), dim3(256), 0, stream,
                     conv1_w, conv2_w, mask_w, q_w, k_w, v_w, WB3, WB1);
  hipLaunchKernelGGL(transpose_kernel, dim3(2048), dim3(256), 0, stream, x, XT);
  hipLaunchKernelGGL(zero_stats_kernel, dim3(1), dim3(256), 0, stream, SUM);
  hipLaunchKernelGGL(conv1_mfma_kernel, dim3(2048), dim3(256), 0, stream,
                     XT, WB3, conv1_b, A, SUM, SQS);
  hipLaunchKernelGGL(finalize_stats_kernel, dim3(4), dim3(256), 0, stream,
                     SUM, SQS, MEAN, RSTD);
  hipLaunchKernelGGL(fused_cmq_kernel, dim3(2048), dim3(256), 0, stream,
                     A, WB3 + 147456, WB3 + 2 * 147456, WB1, MEAN, RSTD,
                     conv2_b, mask_b, q_b, k_b, v_b, out, Mb, Q, K, V);
  hipLaunchKernelGGL(attn_final_kernel, dim3(2048), dim3(256), 0, stream,
                     x, Mb, Q, K, V, k_b, v_b, out);
}